// Round 3
// baseline (322.495 us; speedup 1.0000x reference)
//
#include <hip/hip_runtime.h>
#include <hip/hip_bf16.h>

// ---------------- types / helpers ----------------
using bf16x8 = __attribute__((ext_vector_type(8))) short;
using f32x4  = __attribute__((ext_vector_type(4))) float;

__device__ __forceinline__ unsigned short f2bf_rne(float x) {
    unsigned u = __float_as_uint(x);
    u += 0x7fffu + ((u >> 16) & 1u);
    return (unsigned short)(u >> 16);
}

// ---------------- workspace layout (bytes) ----------------
// dataT padded: 260 rows x 4096 f32 (row f stored at f+1; rows 0,257 zero)
constexpr size_t OFF_DT  = 0;
constexpr size_t OFF_Q1  = OFF_DT  + (size_t)260 * 4096 * 4;   // 4,259,840: [32][4][256] f32 q1
constexpr size_t OFF_BT  = OFF_Q1  + (size_t)32 * 1024 * 4;    // [1024][8192] bf16 pre-swizzled B^T
constexpr size_t OFF_C1P = OFF_BT;                             // [4][127][4096] float2 (aliases BT; dead before castB)
constexpr size_t OFF_W1S = OFF_BT  + (size_t)1024 * 8192 * 2;  // [128][256] bf16 pre-swizzled fc1_w
constexpr size_t OFF_FSI = OFF_W1S + (size_t)128 * 256 * 2;    // [131072] f32 fs_ini (flat srow)
constexpr size_t OFF_FS  = OFF_FSI + (size_t)32 * 4096 * 4;    // [32][4096] f32 fs^T
constexpr size_t OFF_ASC = OFF_FS  + (size_t)32 * 4096 * 4;    // [4096][8192] bf16 A (aliases h2)
constexpr size_t OFF_H2  = OFF_ASC;                            // [131072][256] bf16 h2 (dead before scaleA)
// total = 89,391,104 B (~89 MB)

// ---------------- kernel: transpose data [4096][256] -> dTp rows 1..256 ----------------
__global__ __launch_bounds__(256) void k_transpose(const float* __restrict__ data,
                                                   float* __restrict__ dTp) {
    __shared__ float tile[64][65];
    int bx = blockIdx.x & 63;   // b-tile
    int fx = blockIdx.x >> 6;   // f-tile
    int tx = threadIdx.x & 63, ty4 = threadIdx.x >> 6;
#pragma unroll
    for (int i = 0; i < 16; ++i) {
        int ty = ty4 * 16 + i;
        tile[ty][tx] = data[(bx * 64 + ty) * 256 + fx * 64 + tx];
    }
    __syncthreads();
#pragma unroll
    for (int i = 0; i < 16; ++i) {
        int ty = ty4 * 16 + i;
        dTp[(size_t)(fx * 64 + ty + 1) * 4096 + bx * 64 + tx] = tile[tx][ty];
    }
}

// ---------------- kernel: zero pad rows 0 and 257 of dTp ----------------
__global__ __launch_bounds__(256) void k_zrows(float* __restrict__ dTp) {
    int i = blockIdx.x * 256 + threadIdx.x;  // 4096
    dTp[i] = 0.f;
    dTp[(size_t)257 * 4096 + i] = 0.f;
}

// ---------------- kernel: q1 = conv1(proto) - b1 ----------------
__global__ __launch_bounds__(256) void k_prep_proto(const float* __restrict__ proto,
                                                    const float* __restrict__ w1,
                                                    const float* __restrict__ b1,
                                                    float* __restrict__ q1p) {
    __shared__ float ps[256];
    __shared__ float w1s[20];
    int r = blockIdx.x, tid = threadIdx.x;
    ps[tid] = proto[r * 256 + tid];
    if (tid < 20) w1s[tid] = w1[tid];
    __syncthreads();
    if (tid < 254) {
#pragma unroll
        for (int c = 0; c < 4; ++c) {
            float s = -b1[c];
#pragma unroll
            for (int k = 0; k < 5; ++k) {
                int x = tid + k - 1;
                float xv = (x >= 0 && x < 256) ? ps[x] : 0.f;
                s += w1s[c * 5 + k] * xv;
            }
            q1p[r * 1024 + c * 256 + tid] = s;
        }
    }
}

// ---------------- kernel: c1p[c][l][b] = (conv1(data)[c][2l], [2l+1]) ----------------
// grid 512 x 64: block = (b-group of 64) x (l-chunk of 16)
__global__ __launch_bounds__(64) void k_prep_c1d(const float* __restrict__ dTp,
                                                 const float* __restrict__ w1,
                                                 float2* __restrict__ c1p) {
    int lane = threadIdx.x;
    int bg = blockIdx.x >> 3, ch = blockIdx.x & 7;
    int l0 = ch << 4;
    int nl = (ch == 7) ? 15 : 16;
    int b = (bg << 6) + lane;
    float w1r[20];
#pragma unroll
    for (int i = 0; i < 20; ++i) w1r[i] = w1[i];
    const float* dp = dTp + (size_t)(2 * l0) * 4096 + b;  // padded row index = f+1
    float d[6];
#pragma unroll
    for (int i = 0; i < 6; ++i) d[i] = dp[(size_t)i * 4096];
    dp += (size_t)6 * 4096;
    float2* outp = c1p + b;
    for (int li = 0; li < nl; ++li) {
        int l = l0 + li;
#pragma unroll
        for (int c = 0; c < 4; ++c) {
            float s0 = 0.f, s1 = 0.f;
#pragma unroll
            for (int k = 0; k < 5; ++k) {
                s0 += w1r[c * 5 + k] * d[k];
                s1 += w1r[c * 5 + k] * d[k + 1];
            }
            outp[(size_t)(c * 127 + l) * 4096] = make_float2(s0, s1);
        }
        d[0] = d[2]; d[1] = d[3]; d[2] = d[4]; d[3] = d[5];
        d[4] = dp[0];
        d[5] = dp[4096];
        dp += 8192;
    }
}

// ---------------- kernel: B^T cast, zero-pad cols 1000..1023, pre-swizzled ----------------
__global__ __launch_bounds__(256) void k_castB(const float* __restrict__ cw,
                                               unsigned short* __restrict__ BT) {
    int g = blockIdx.x * 256 + threadIdx.x;   // 1,048,576 = 8192 k * 128 c-groups
    int k = g & 8191;
    int c0 = (g >> 13) << 3;
#pragma unroll
    for (int i = 0; i < 8; ++i) {
        int c = c0 + i;
        float v = (c < 1000) ? cw[k * 1000 + c] : 0.f;
        int byte = c * 16384 + ((k >> 6) << 7) + (((((k >> 3) & 7)) ^ (c & 7)) << 4) + ((k & 7) << 1);
        *(unsigned short*)((char*)BT + byte) = f2bf_rne(v);
    }
}

// ---------------- kernel: fc1_w cast -> [128 col][256 k] bf16 pre-swizzled ----------------
// k-permutation: k = j2*4 + c  <->  f_att = (k&3)*62 + (k>>2)
__global__ __launch_bounds__(256) void k_castW(const float* __restrict__ fc1w,
                                               unsigned short* __restrict__ W1s) {
    int idx = blockIdx.x * 256 + threadIdx.x;  // 32768
    int col = idx >> 8, k = idx & 255;
    float v = 0.f;
    if (col < 124 && k < 248) {
        int f = (k & 3) * 62 + (k >> 2);
        v = fc1w[f * 124 + col];
    }
    int byte = col * 512 + ((k >> 6) << 7) + ((((k >> 3) & 7) ^ (col & 7)) << 4) + ((k & 7) << 1);
    *(unsigned short*)((char*)W1s + byte) = f2bf_rne(v);
}

// ---------------- kernel: gating conv2 (sample-per-lane) -> h2 bf16 pre-swizzled ----------------
// wave job = (r, b-chunk of 64). grid 1024 x 128 (2048 wave jobs). Zero __syncthreads.
__global__ __launch_bounds__(128) void k_conv2(const float2* __restrict__ c1p,
                                               const float* __restrict__ q1p,
                                               const float* __restrict__ w2,
                                               const float* __restrict__ b2,
                                               char* __restrict__ h2c) {
    __shared__ unsigned short Tsh[2 * 64 * 72];

    int tid = threadIdx.x, lane = tid & 63, w = tid >> 6;
    int job = blockIdx.x * 2 + w;
    int r  = __builtin_amdgcn_readfirstlane(job >> 6);
    int b0 = __builtin_amdgcn_readfirstlane((job & 63) << 6);
    int b = b0 + lane;
    int rb0 = r * 4096 + b0;
    unsigned short* T = Tsh + w * (64 * 72);

    float w2r[80], b2r[4];
#pragma unroll
    for (int i = 0; i < 80; ++i) w2r[i] = w2[i];
#pragma unroll
    for (int i = 0; i < 4; ++i) b2r[i] = b2[i];
    const float2* q2 = (const float2*)(q1p + r * 1024);  // q2[c*128 + l]
    const float2* cp = c1p + b;

    auto pooled = [&](int l, float o[4]) {
#pragma unroll
        for (int c = 0; c < 4; ++c) {
            float2 v = cp[(size_t)(c * 127 + l) * 4096];
            float2 q = q2[c * 128 + l];
            o[c] = 0.5f * (fmaxf(v.x - q.x, 0.f) + fmaxf(v.y - q.y, 0.f));
        }
    };

    // rolling window p[ci][0..5] = pooled1[2*j2-1 .. 2*j2+4] (index -1 = pad 0)
    float p[4][6];
#pragma unroll
    for (int c = 0; c < 4; ++c) p[c][0] = 0.f;
    for (int l = 0; l < 5; ++l) {
        float pv[4];
        pooled(l, pv);
#pragma unroll
        for (int c = 0; c < 4; ++c) p[c][l + 1] = pv[c];
    }

#pragma unroll 1
    for (int j2 = 0; j2 < 62; ++j2) {
        // conv2 (+b2) at t=2j2, 2j2+1; relu; avgpool2
        float u0[4], u1[4];
#pragma unroll
        for (int c = 0; c < 4; ++c) { u0[c] = b2r[c]; u1[c] = b2r[c]; }
#pragma unroll
        for (int c = 0; c < 4; ++c)
#pragma unroll
            for (int ci = 0; ci < 4; ++ci)
#pragma unroll
                for (int k = 0; k < 5; ++k) {
                    float wv = w2r[(c * 4 + ci) * 5 + k];
                    u0[c] += wv * p[ci][k];
                    u1[c] += wv * p[ci][k + 1];
                }
        unsigned pk0, pk1;
        {
            float h0 = 0.5f * (fmaxf(u0[0], 0.f) + fmaxf(u1[0], 0.f));
            float h1 = 0.5f * (fmaxf(u0[1], 0.f) + fmaxf(u1[1], 0.f));
            float h2v = 0.5f * (fmaxf(u0[2], 0.f) + fmaxf(u1[2], 0.f));
            float h3 = 0.5f * (fmaxf(u0[3], 0.f) + fmaxf(u1[3], 0.f));
            pk0 = (unsigned)f2bf_rne(h0) | ((unsigned)f2bf_rne(h1) << 16);
            pk1 = (unsigned)f2bf_rne(h2v) | ((unsigned)f2bf_rne(h3) << 16);
        }
        // k-index = j2*4 + c ; write into per-wave LDS tile at col (j2&15)*4
        {
            uint2 vv; vv.x = pk0; vv.y = pk1;
            *(uint2*)(T + lane * 72 + (j2 & 15) * 4) = vv;
        }
        if (j2 == 61) {  // zero-pad k 248..255 (cols 56..63 of chunk 3)
            uint4 z; z.x = z.y = z.z = z.w = 0u;
            *(uint4*)(T + lane * 72 + 56) = z;
        }
        // flush every 16 j2 (k-chunk of 64), pre-swizzled global rows
        if ((j2 & 15) == 15 || j2 == 61) {
            int chunk = j2 >> 4;
            int g = lane & 7;
#pragma unroll
            for (int i = 0; i < 8; ++i) {
                int sL = i * 8 + (lane >> 3);
                bf16x8 v = *(const bf16x8*)(T + sL * 72 + g * 8);
                int srow = rb0 + sL;
                size_t byte = (size_t)srow * 512 + (size_t)(chunk * 128) + (size_t)((g ^ (srow & 7)) << 4);
                *(bf16x8*)(h2c + byte) = v;
            }
        }
        // advance window: shift 2, compute pooled1 l = 2j2+5, 2j2+6
        if (j2 < 61) {
#pragma unroll
            for (int c = 0; c < 4; ++c) {
                p[c][0] = p[c][2]; p[c][1] = p[c][3];
                p[c][2] = p[c][4]; p[c][3] = p[c][5];
            }
            float pv[4];
            pooled(2 * j2 + 5, pv);
#pragma unroll
            for (int c = 0; c < 4; ++c) p[c][4] = pv[c];
            pooled(2 * j2 + 6, pv);
#pragma unroll
            for (int c = 0; c < 4; ++c) p[c][5] = pv[c];
        }
    }
}

// ---------------- kernel: fc1+relu+fc2+tanh as register MFMA GEMM ----------------
__global__ __launch_bounds__(256) void k_fc(const char* __restrict__ h2,
                                            const char* __restrict__ W1s,
                                            const float* __restrict__ fc1b,
                                            const float* __restrict__ fc2w,
                                            const float* __restrict__ fc2b,
                                            float* __restrict__ fsiniT) {
    int tid = threadIdx.x, lane = tid & 63, w = tid >> 6;
    int row0 = blockIdx.x * 128 + w * 32;
    int lr = lane & 15, g = lane >> 4, rxor = lr & 7;

    f32x4 acc[2][8] = {};

    const char* arow0 = h2 + (size_t)(row0 + lr) * 512;
    const char* arow1 = arow0 + 16 * 512;

    auto inrowf = [&](int ks) {
        return ((ks >> 1) << 7) + ((((ks * 4 + g) & 7) ^ rxor) << 4);
    };

    bf16x8 a0 = *(const bf16x8*)(arow0 + inrowf(0));
    bf16x8 a1 = *(const bf16x8*)(arow1 + inrowf(0));

#pragma unroll
    for (int ks = 0; ks < 8; ++ks) {
        int ir = inrowf(ks);
        bf16x8 bfr[8];
#pragma unroll
        for (int nf = 0; nf < 8; ++nf)
            bfr[nf] = *(const bf16x8*)(W1s + (nf * 16 + lr) * 512 + ir);
        bf16x8 an0 = a0, an1 = a1;
        if (ks < 7) {
            int ir2 = inrowf(ks + 1);
            an0 = *(const bf16x8*)(arow0 + ir2);
            an1 = *(const bf16x8*)(arow1 + ir2);
        }
#pragma unroll
        for (int nf = 0; nf < 8; ++nf) {
            acc[0][nf] = __builtin_amdgcn_mfma_f32_16x16x32_bf16(a0, bfr[nf], acc[0][nf], 0, 0, 0);
            acc[1][nf] = __builtin_amdgcn_mfma_f32_16x16x32_bf16(a1, bfr[nf], acc[1][nf], 0, 0, 0);
        }
        a0 = an0; a1 = an1;
    }

    float zp[2][4] = {};
#pragma unroll
    for (int nf = 0; nf < 8; ++nf) {
        int col = nf * 16 + lr;
        float b1v = (col < 124) ? fc1b[col] : 0.f;
        float w2v = (col < 124) ? fc2w[col] : 0.f;
#pragma unroll
        for (int mf = 0; mf < 2; ++mf)
#pragma unroll
            for (int q = 0; q < 4; ++q) {
                float h = fmaxf(acc[mf][nf][q] + b1v, 0.f);
                zp[mf][q] += h * w2v;
            }
    }
#pragma unroll
    for (int off = 1; off < 16; off <<= 1) {
#pragma unroll
        for (int mf = 0; mf < 2; ++mf)
#pragma unroll
            for (int q = 0; q < 4; ++q)
                zp[mf][q] += __shfl_xor(zp[mf][q], off, 64);
    }
    if (lr == 0) {
        float c2 = fc2b[0];
#pragma unroll
        for (int mf = 0; mf < 2; ++mf)
#pragma unroll
            for (int q = 0; q < 4; ++q) {
                int srow = row0 + mf * 16 + g * 4 + q;
                fsiniT[srow] = tanhf(zp[mf][q] + c2);
            }
    }
}

// ---------------- kernel: softmax over rules ----------------
__global__ __launch_bounds__(256) void k_softmax(const float* __restrict__ fsiniT,
                                                 float* __restrict__ fsT) {
    int b = blockIdx.x * 256 + threadIdx.x;  // 4096
    float v[32];
    float m = -1e30f;
#pragma unroll
    for (int r = 0; r < 32; ++r) { v[r] = fsiniT[r * 4096 + b]; m = fmaxf(m, v[r]); }
    float s = 0.f;
#pragma unroll
    for (int r = 0; r < 32; ++r) { v[r] = expf(v[r] - m); s += v[r]; }
    float inv = 1.f / s;
#pragma unroll
    for (int r = 0; r < 32; ++r) fsT[r * 4096 + b] = v[r] * inv;
}

// ---------------- kernel: A[b][k] = bf16(fs[b,r]*data[b,f]), pre-swizzled ----------------
__global__ __launch_bounds__(256) void k_scaleA(const float* __restrict__ data,
                                                const float* __restrict__ fsT,
                                                unsigned short* __restrict__ Asc) {
    int g = blockIdx.x * 256 + threadIdx.x;  // 4,194,304 = 4096 b * 1024 kg
    int b = g >> 10, kg = g & 1023;
    int r = kg >> 5, f0 = (kg & 31) << 3;
    float fs = fsT[r * 4096 + b];
    const float4* dp = (const float4*)(data + b * 256 + f0);
    float4 v0 = dp[0], v1 = dp[1];
    float vals[8] = {v0.x, v0.y, v0.z, v0.w, v1.x, v1.y, v1.z, v1.w};
    uint4 o;
    unsigned* op = (unsigned*)&o;
#pragma unroll
    for (int i = 0; i < 4; ++i) {
        unsigned lo = f2bf_rne(vals[2 * i] * fs);
        unsigned hi = f2bf_rne(vals[2 * i + 1] * fs);
        op[i] = lo | (hi << 16);
    }
    int byte = b * 16384 + ((kg & ~7) << 4) + (((kg & 7) ^ (b & 7)) << 4);
    *(uint4*)((char*)Asc + byte) = o;
}

// ---------------- kernel: GEMM [4096 x 8192] x [8192 x 1024] + fs@consq_b epilogue ----------------
__global__ __launch_bounds__(512) void k_gemm(const unsigned short* __restrict__ Asc,
                                              const unsigned short* __restrict__ BT,
                                              const float* __restrict__ fsT,
                                              const float* __restrict__ cb,
                                              float* __restrict__ out) {
    __shared__ unsigned short As[8192];  // 128 rows x 64 k bf16 (swizzled)
    __shared__ unsigned short Bs[8192];  // 128 cols x 64 k bf16 (swizzled)
    int tid = threadIdx.x, lane = tid & 63, w = tid >> 6;
    int wm = w >> 2, wn = w & 3;
    int mt = blockIdx.x >> 3, nt = blockIdx.x & 7;
    int row0 = mt << 7, col0 = nt << 7;

    f32x4 acc[4][2] = {};

    const char* Ab = (const char*)Asc;
    const char* Bb = (const char*)BT;
    int flat0 = tid * 16, flat1 = tid * 16 + 8192;
    int rowl0 = flat0 >> 7, colB0 = flat0 & 127;
    int rowl1 = flat1 >> 7, colB1 = flat1 & 127;
    const char* aSrc0 = Ab + (row0 + rowl0) * 16384 + colB0;
    const char* aSrc1 = Ab + (row0 + rowl1) * 16384 + colB1;
    const char* bSrc0 = Bb + (col0 + rowl0) * 16384 + colB0;
    const char* bSrc1 = Bb + (col0 + rowl1) * 16384 + colB1;

    uint4 ra0 = *(const uint4*)aSrc0, ra1 = *(const uint4*)aSrc1;
    uint4 rb0 = *(const uint4*)bSrc0, rb1 = *(const uint4*)bSrc1;

    for (int kt = 0; kt < 128; ++kt) {
        __syncthreads();
        *(uint4*)((char*)As + flat0) = ra0;
        *(uint4*)((char*)As + flat1) = ra1;
        *(uint4*)((char*)Bs + flat0) = rb0;
        *(uint4*)((char*)Bs + flat1) = rb1;
        if (kt < 127) {
            int off = (kt + 1) << 7;
            ra0 = *(const uint4*)(aSrc0 + off);
            ra1 = *(const uint4*)(aSrc1 + off);
            rb0 = *(const uint4*)(bSrc0 + off);
            rb1 = *(const uint4*)(bSrc1 + off);
        }
        __syncthreads();
#pragma unroll
        for (int s = 0; s < 2; ++s) {
            bf16x8 af[4], bfv[2];
            int colByte = ((s << 5) + ((lane >> 4) << 3)) << 1;
#pragma unroll
            for (int mi = 0; mi < 4; ++mi) {
                int rowA = (wm << 6) + (mi << 4) + (lane & 15);
                int byte = (rowA << 7) + colByte;
                af[mi] = *(const bf16x8*)((const char*)As + (byte ^ ((rowA & 7) << 4)));
            }
#pragma unroll
            for (int ni = 0; ni < 2; ++ni) {
                int rowB = (wn << 5) + (ni << 4) + (lane & 15);
                int byte = (rowB << 7) + colByte;
                bfv[ni] = *(const bf16x8*)((const char*)Bs + (byte ^ ((rowB & 7) << 4)));
            }
#pragma unroll
            for (int mi = 0; mi < 4; ++mi)
#pragma unroll
                for (int ni = 0; ni < 2; ++ni)
                    acc[mi][ni] = __builtin_amdgcn_mfma_f32_16x16x32_bf16(af[mi], bfv[ni], acc[mi][ni], 0, 0, 0);
        }
    }

    int cA = col0 + (wn << 5) + (lane & 15);
    int cB2 = cA + 16;
    int rbase = row0 + (wm << 6) + ((lane >> 4) << 2);
    float bias[4][4][2];
#pragma unroll
    for (int mi = 0; mi < 4; ++mi)
#pragma unroll
        for (int q = 0; q < 4; ++q) { bias[mi][q][0] = 0.f; bias[mi][q][1] = 0.f; }

    for (int rr = 0; rr < 32; ++rr) {
        float cb0 = (cA < 1000) ? cb[rr * 1000 + cA] : 0.f;
        float cb1 = (cB2 < 1000) ? cb[rr * 1000 + cB2] : 0.f;
        const float* fcol = fsT + rr * 4096;
#pragma unroll
        for (int mi = 0; mi < 4; ++mi)
#pragma unroll
            for (int q = 0; q < 4; ++q) {
                float fsv = fcol[rbase + mi * 16 + q];
                bias[mi][q][0] += fsv * cb0;
                bias[mi][q][1] += fsv * cb1;
            }
    }
#pragma unroll
    for (int mi = 0; mi < 4; ++mi)
#pragma unroll
        for (int q = 0; q < 4; ++q) {
            int row = rbase + mi * 16 + q;
            if (cA < 1000) out[row * 1000 + cA] = acc[mi][0][q] + bias[mi][q][0];
            if (cB2 < 1000) out[row * 1000 + cB2] = acc[mi][1][q] + bias[mi][q][1];
        }
}

// ---------------- launch ----------------
extern "C" void kernel_launch(void* const* d_in, const int* in_sizes, int n_in,
                              void* d_out, int out_size, void* d_ws, size_t ws_size,
                              hipStream_t stream) {
    const float* data  = (const float*)d_in[0];
    const float* proto = (const float*)d_in[1];
    const float* w1    = (const float*)d_in[2];
    const float* b1    = (const float*)d_in[3];
    const float* w2    = (const float*)d_in[4];
    const float* b2    = (const float*)d_in[5];
    const float* fc1w  = (const float*)d_in[6];
    const float* fc1b  = (const float*)d_in[7];
    const float* fc2w  = (const float*)d_in[8];
    const float* fc2b  = (const float*)d_in[9];
    const float* cw    = (const float*)d_in[10];
    const float* cbias = (const float*)d_in[11];
    float* out = (float*)d_out;
    char* ws = (char*)d_ws;

    float* dTp             = (float*)(ws + OFF_DT);
    float* q1p             = (float*)(ws + OFF_Q1);
    float2* c1p            = (float2*)(ws + OFF_C1P);
    unsigned short* BT     = (unsigned short*)(ws + OFF_BT);
    unsigned short* W1s    = (unsigned short*)(ws + OFF_W1S);
    float* fsiniT          = (float*)(ws + OFF_FSI);
    float* fsT             = (float*)(ws + OFF_FS);
    unsigned short* Asc    = (unsigned short*)(ws + OFF_ASC);
    char* h2c              = (char*)(ws + OFF_H2);

    hipLaunchKernelGGL(k_transpose, dim3(256), dim3(256), 0, stream, data, dTp);
    hipLaunchKernelGGL(k_zrows, dim3(16), dim3(256), 0, stream, dTp);
    hipLaunchKernelGGL(k_prep_proto, dim3(32), dim3(256), 0, stream, proto, w1, b1, q1p);
    hipLaunchKernelGGL(k_prep_c1d, dim3(512), dim3(64), 0, stream, dTp, w1, c1p);
    hipLaunchKernelGGL(k_conv2, dim3(1024), dim3(128), 0, stream, c1p, q1p, w2, b2, h2c);
    // castB AFTER conv2: BT region aliases c1p
    hipLaunchKernelGGL(k_castB, dim3(4096), dim3(256), 0, stream, cw, BT);
    hipLaunchKernelGGL(k_castW, dim3(128), dim3(256), 0, stream, fc1w, W1s);
    hipLaunchKernelGGL(k_fc, dim3(1024), dim3(256), 0, stream,
                       h2c, (const char*)W1s, fc1b, fc2w, fc2b, fsiniT);
    hipLaunchKernelGGL(k_softmax, dim3(16), dim3(256), 0, stream, fsiniT, fsT);
    hipLaunchKernelGGL(k_scaleA, dim3(16384), dim3(256), 0, stream, data, fsT, Asc);
    hipLaunchKernelGGL(k_gemm, dim3(256), dim3(512), 0, stream, Asc, BT, fsT, cbias, out);
}

// Round 4
// 295.620 us; speedup vs baseline: 1.0909x; 1.0909x over previous
//
#include <hip/hip_runtime.h>
#include <hip/hip_bf16.h>

// ---------------- types / helpers ----------------
using bf16x8 = __attribute__((ext_vector_type(8))) short;
using f32x4  = __attribute__((ext_vector_type(4))) float;

__device__ __forceinline__ unsigned short f2bf_rne(float x) {
    unsigned u = __float_as_uint(x);
    u += 0x7fffu + ((u >> 16) & 1u);
    return (unsigned short)(u >> 16);
}

// ---------------- workspace layout (bytes) ----------------
// dataT padded: 260 rows x 4096 f32 (row f stored at f+1; rows 0,257 zero)
constexpr size_t OFF_DT  = 0;
constexpr size_t OFF_Q1  = OFF_DT  + (size_t)260 * 4096 * 4;   // [32][4][256] f32 q1
constexpr size_t OFF_BT  = OFF_Q1  + (size_t)32 * 1024 * 4;    // [1024][8192] bf16 pre-swizzled B^T
constexpr size_t OFF_C1P = OFF_BT;                             // [4][127][4096] float2 (aliases BT; dead before castB)
constexpr size_t OFF_W1S = OFF_BT  + (size_t)1024 * 8192 * 2;  // [128][256] bf16 pre-swizzled fc1_w
constexpr size_t OFF_FSI = OFF_W1S + (size_t)128 * 256 * 2;    // [131072] f32 fs_ini (flat srow)
constexpr size_t OFF_FS  = OFF_FSI + (size_t)32 * 4096 * 4;    // [32][4096] f32 fs^T
constexpr size_t OFF_ASC = OFF_FS  + (size_t)32 * 4096 * 4;    // [4096][8192] bf16 A (aliases h2)
constexpr size_t OFF_H2  = OFF_ASC;                            // [131072][256] bf16 h2 (dead before scaleA)
// total = ~89 MB

// ---------------- kernel: transpose data [4096][256] -> dTp rows 1..256 ----------------
__global__ __launch_bounds__(256) void k_transpose(const float* __restrict__ data,
                                                   float* __restrict__ dTp) {
    __shared__ float tile[64][65];
    int bx = blockIdx.x & 63;   // b-tile
    int fx = blockIdx.x >> 6;   // f-tile
    int tx = threadIdx.x & 63, ty4 = threadIdx.x >> 6;
#pragma unroll
    for (int i = 0; i < 16; ++i) {
        int ty = ty4 * 16 + i;
        tile[ty][tx] = data[(bx * 64 + ty) * 256 + fx * 64 + tx];
    }
    __syncthreads();
#pragma unroll
    for (int i = 0; i < 16; ++i) {
        int ty = ty4 * 16 + i;
        dTp[(size_t)(fx * 64 + ty + 1) * 4096 + bx * 64 + tx] = tile[tx][ty];
    }
}

// ---------------- kernel: zero pad rows 0 and 257 of dTp ----------------
__global__ __launch_bounds__(256) void k_zrows(float* __restrict__ dTp) {
    int i = blockIdx.x * 256 + threadIdx.x;  // 4096
    dTp[i] = 0.f;
    dTp[(size_t)257 * 4096 + i] = 0.f;
}

// ---------------- kernel: q1 = conv1(proto) - b1 ----------------
__global__ __launch_bounds__(256) void k_prep_proto(const float* __restrict__ proto,
                                                    const float* __restrict__ w1,
                                                    const float* __restrict__ b1,
                                                    float* __restrict__ q1p) {
    __shared__ float ps[256];
    __shared__ float w1s[20];
    int r = blockIdx.x, tid = threadIdx.x;
    ps[tid] = proto[r * 256 + tid];
    if (tid < 20) w1s[tid] = w1[tid];
    __syncthreads();
    if (tid < 254) {
#pragma unroll
        for (int c = 0; c < 4; ++c) {
            float s = -b1[c];
#pragma unroll
            for (int k = 0; k < 5; ++k) {
                int x = tid + k - 1;
                float xv = (x >= 0 && x < 256) ? ps[x] : 0.f;
                s += w1s[c * 5 + k] * xv;
            }
            q1p[r * 1024 + c * 256 + tid] = s;
        }
    }
}

// ---------------- kernel: c1p[c][l][b] = (conv1(data)[c][2l], [2l+1]) ----------------
// grid 512 x 64: block = (b-group of 64) x (l-chunk of 16)
__global__ __launch_bounds__(64) void k_prep_c1d(const float* __restrict__ dTp,
                                                 const float* __restrict__ w1,
                                                 float2* __restrict__ c1p) {
    int lane = threadIdx.x;
    int bg = blockIdx.x >> 3, ch = blockIdx.x & 7;
    int l0 = ch << 4;
    int nl = (ch == 7) ? 15 : 16;
    int b = (bg << 6) + lane;
    float w1r[20];
#pragma unroll
    for (int i = 0; i < 20; ++i) w1r[i] = w1[i];
    const float* dp = dTp + (size_t)(2 * l0) * 4096 + b;  // padded row index = f+1
    float d[6];
#pragma unroll
    for (int i = 0; i < 6; ++i) d[i] = dp[(size_t)i * 4096];
    dp += (size_t)6 * 4096;
    float2* outp = c1p + b;
    for (int li = 0; li < nl; ++li) {
        int l = l0 + li;
#pragma unroll
        for (int c = 0; c < 4; ++c) {
            float s0 = 0.f, s1 = 0.f;
#pragma unroll
            for (int k = 0; k < 5; ++k) {
                s0 += w1r[c * 5 + k] * d[k];
                s1 += w1r[c * 5 + k] * d[k + 1];
            }
            outp[(size_t)(c * 127 + l) * 4096] = make_float2(s0, s1);
        }
        d[0] = d[2]; d[1] = d[3]; d[2] = d[4]; d[3] = d[5];
        d[4] = dp[0];
        d[5] = dp[4096];
        dp += 8192;
    }
}

// ---------------- kernel: B^T cast, zero-pad cols 1000..1023, pre-swizzled ----------------
__global__ __launch_bounds__(256) void k_castB(const float* __restrict__ cw,
                                               unsigned short* __restrict__ BT) {
    int g = blockIdx.x * 256 + threadIdx.x;   // 1,048,576 = 8192 k * 128 c-groups
    int k = g & 8191;
    int c0 = (g >> 13) << 3;
#pragma unroll
    for (int i = 0; i < 8; ++i) {
        int c = c0 + i;
        float v = (c < 1000) ? cw[k * 1000 + c] : 0.f;
        int byte = c * 16384 + ((k >> 6) << 7) + (((((k >> 3) & 7)) ^ (c & 7)) << 4) + ((k & 7) << 1);
        *(unsigned short*)((char*)BT + byte) = f2bf_rne(v);
    }
}

// ---------------- kernel: fc1_w cast -> [128 col][256 k] bf16 pre-swizzled ----------------
// k-permutation: k = j2*4 + c  <->  f_att = (k&3)*62 + (k>>2)
__global__ __launch_bounds__(256) void k_castW(const float* __restrict__ fc1w,
                                               unsigned short* __restrict__ W1s) {
    int idx = blockIdx.x * 256 + threadIdx.x;  // 32768
    int col = idx >> 8, k = idx & 255;
    float v = 0.f;
    if (col < 124 && k < 248) {
        int f = (k & 3) * 62 + (k >> 2);
        v = fc1w[f * 124 + col];
    }
    int byte = col * 512 + ((k >> 6) << 7) + ((((k >> 3) & 7) ^ (col & 7)) << 4) + ((k & 7) << 1);
    *(unsigned short*)((char*)W1s + byte) = f2bf_rne(v);
}

// ---------------- kernel: gating conv2 (sample-per-lane) -> h2 bf16 pre-swizzled ----------------
// 1 wave per block, grid 2048. launch_bounds(64,2) -> 256-VGPR budget so w2r[80] stays
// register-resident. Depth-2 prefetch of c1p/q window loads hides LLC latency.
__global__ __launch_bounds__(64, 2) void k_conv2(const float2* __restrict__ c1p,
                                                 const float* __restrict__ q1p,
                                                 const float* __restrict__ w2,
                                                 const float* __restrict__ b2,
                                                 char* __restrict__ h2c) {
    __shared__ unsigned short T[64 * 72];

    int lane = threadIdx.x;
    int job = blockIdx.x;
    int r  = job >> 6;
    int b0 = (job & 63) << 6;
    int b = b0 + lane;
    int rb0 = r * 4096 + b0;

    float w2r[80], b2r[4];
#pragma unroll
    for (int i = 0; i < 80; ++i) w2r[i] = w2[i];
#pragma unroll
    for (int i = 0; i < 4; ++i) b2r[i] = b2[i];
    const float2* q2 = (const float2*)(q1p + r * 1024);  // q2[c*128 + l]
    const float2* cp = c1p + b;

    // window p[ci][0..5] = pooled1[2*j2-1 .. 2*j2+4]
    float p[4][6];
#pragma unroll
    for (int c = 0; c < 4; ++c) p[c][0] = 0.f;
#pragma unroll
    for (int l = 0; l < 5; ++l) {
#pragma unroll
        for (int c = 0; c < 4; ++c) {
            float2 v = cp[(size_t)(c * 127 + l) * 4096];
            float2 q = q2[c * 128 + l];
            p[c][l + 1] = 0.5f * (fmaxf(v.x - q.x, 0.f) + fmaxf(v.y - q.y, 0.f));
        }
    }
    // prefetch pipeline: (va,qa)=l=5, (vb,qb)=l=6 (consumed at end of j2=0)
    float2 va[4], vb[4], qa[4], qb[4];
#pragma unroll
    for (int c = 0; c < 4; ++c) {
        va[c] = cp[(size_t)(c * 127 + 5) * 4096];
        vb[c] = cp[(size_t)(c * 127 + 6) * 4096];
        qa[c] = q2[c * 128 + 5];
        qb[c] = q2[c * 128 + 6];
    }

#pragma unroll 2
    for (int j2 = 0; j2 < 62; ++j2) {
        // issue loads for l = 2*j2+7, 2*j2+8 (consumed at end of iteration j2+1)
        float2 na[4], nb[4], nqa[4], nqb[4];
        if (j2 < 60) {
            int la = 2 * j2 + 7, lb = 2 * j2 + 8;
#pragma unroll
            for (int c = 0; c < 4; ++c) {
                na[c]  = cp[(size_t)(c * 127 + la) * 4096];
                nb[c]  = cp[(size_t)(c * 127 + lb) * 4096];
                nqa[c] = q2[c * 128 + la];
                nqb[c] = q2[c * 128 + lb];
            }
        }
        // conv2 (+b2) at t=2j2, 2j2+1; relu; avgpool2
        float u0[4], u1[4];
#pragma unroll
        for (int c = 0; c < 4; ++c) { u0[c] = b2r[c]; u1[c] = b2r[c]; }
#pragma unroll
        for (int c = 0; c < 4; ++c)
#pragma unroll
            for (int ci = 0; ci < 4; ++ci)
#pragma unroll
                for (int k = 0; k < 5; ++k) {
                    float wv = w2r[(c * 4 + ci) * 5 + k];
                    u0[c] += wv * p[ci][k];
                    u1[c] += wv * p[ci][k + 1];
                }
        unsigned pk0, pk1;
        {
            float h0 = 0.5f * (fmaxf(u0[0], 0.f) + fmaxf(u1[0], 0.f));
            float h1 = 0.5f * (fmaxf(u0[1], 0.f) + fmaxf(u1[1], 0.f));
            float h2v = 0.5f * (fmaxf(u0[2], 0.f) + fmaxf(u1[2], 0.f));
            float h3 = 0.5f * (fmaxf(u0[3], 0.f) + fmaxf(u1[3], 0.f));
            pk0 = (unsigned)f2bf_rne(h0) | ((unsigned)f2bf_rne(h1) << 16);
            pk1 = (unsigned)f2bf_rne(h2v) | ((unsigned)f2bf_rne(h3) << 16);
        }
        {
            uint2 vv; vv.x = pk0; vv.y = pk1;
            *(uint2*)(T + lane * 72 + (j2 & 15) * 4) = vv;
        }
        if (j2 == 61) {  // zero-pad k 248..255 (cols 56..63 of chunk 3)
            uint4 z; z.x = z.y = z.z = z.w = 0u;
            *(uint4*)(T + lane * 72 + 56) = z;
        }
        // flush every 16 j2 (k-chunk of 64), pre-swizzled global rows
        if ((j2 & 15) == 15 || j2 == 61) {
            int chunk = j2 >> 4;
            int g = lane & 7;
#pragma unroll
            for (int i = 0; i < 8; ++i) {
                int sL = i * 8 + (lane >> 3);
                bf16x8 v = *(const bf16x8*)(T + sL * 72 + g * 8);
                int srow = rb0 + sL;
                size_t byte = (size_t)srow * 512 + (size_t)(chunk * 128) + (size_t)((g ^ (srow & 7)) << 4);
                *(bf16x8*)(h2c + byte) = v;
            }
        }
        // advance window: consume prefetched l = 2*j2+5, 2*j2+6
        if (j2 < 61) {
#pragma unroll
            for (int c = 0; c < 4; ++c) {
                p[c][0] = p[c][2]; p[c][1] = p[c][3];
                p[c][2] = p[c][4]; p[c][3] = p[c][5];
                p[c][4] = 0.5f * (fmaxf(va[c].x - qa[c].x, 0.f) + fmaxf(va[c].y - qa[c].y, 0.f));
                p[c][5] = 0.5f * (fmaxf(vb[c].x - qb[c].x, 0.f) + fmaxf(vb[c].y - qb[c].y, 0.f));
                va[c] = na[c]; vb[c] = nb[c]; qa[c] = nqa[c]; qb[c] = nqb[c];
            }
        }
    }
}

// ---------------- kernel: fc1+relu+fc2+tanh as register MFMA GEMM ----------------
__global__ __launch_bounds__(256) void k_fc(const char* __restrict__ h2,
                                            const char* __restrict__ W1s,
                                            const float* __restrict__ fc1b,
                                            const float* __restrict__ fc2w,
                                            const float* __restrict__ fc2b,
                                            float* __restrict__ fsiniT) {
    int tid = threadIdx.x, lane = tid & 63, w = tid >> 6;
    int row0 = blockIdx.x * 128 + w * 32;
    int lr = lane & 15, g = lane >> 4, rxor = lr & 7;

    f32x4 acc[2][8] = {};

    const char* arow0 = h2 + (size_t)(row0 + lr) * 512;
    const char* arow1 = arow0 + 16 * 512;

    auto inrowf = [&](int ks) {
        return ((ks >> 1) << 7) + ((((ks * 4 + g) & 7) ^ rxor) << 4);
    };

    bf16x8 a0 = *(const bf16x8*)(arow0 + inrowf(0));
    bf16x8 a1 = *(const bf16x8*)(arow1 + inrowf(0));

#pragma unroll
    for (int ks = 0; ks < 8; ++ks) {
        int ir = inrowf(ks);
        bf16x8 bfr[8];
#pragma unroll
        for (int nf = 0; nf < 8; ++nf)
            bfr[nf] = *(const bf16x8*)(W1s + (nf * 16 + lr) * 512 + ir);
        bf16x8 an0 = a0, an1 = a1;
        if (ks < 7) {
            int ir2 = inrowf(ks + 1);
            an0 = *(const bf16x8*)(arow0 + ir2);
            an1 = *(const bf16x8*)(arow1 + ir2);
        }
#pragma unroll
        for (int nf = 0; nf < 8; ++nf) {
            acc[0][nf] = __builtin_amdgcn_mfma_f32_16x16x32_bf16(a0, bfr[nf], acc[0][nf], 0, 0, 0);
            acc[1][nf] = __builtin_amdgcn_mfma_f32_16x16x32_bf16(a1, bfr[nf], acc[1][nf], 0, 0, 0);
        }
        a0 = an0; a1 = an1;
    }

    float zp[2][4] = {};
#pragma unroll
    for (int nf = 0; nf < 8; ++nf) {
        int col = nf * 16 + lr;
        float b1v = (col < 124) ? fc1b[col] : 0.f;
        float w2v = (col < 124) ? fc2w[col] : 0.f;
#pragma unroll
        for (int mf = 0; mf < 2; ++mf)
#pragma unroll
            for (int q = 0; q < 4; ++q) {
                float h = fmaxf(acc[mf][nf][q] + b1v, 0.f);
                zp[mf][q] += h * w2v;
            }
    }
#pragma unroll
    for (int off = 1; off < 16; off <<= 1) {
#pragma unroll
        for (int mf = 0; mf < 2; ++mf)
#pragma unroll
            for (int q = 0; q < 4; ++q)
                zp[mf][q] += __shfl_xor(zp[mf][q], off, 64);
    }
    if (lr == 0) {
        float c2 = fc2b[0];
#pragma unroll
        for (int mf = 0; mf < 2; ++mf)
#pragma unroll
            for (int q = 0; q < 4; ++q) {
                int srow = row0 + mf * 16 + g * 4 + q;
                fsiniT[srow] = tanhf(zp[mf][q] + c2);
            }
    }
}

// ---------------- kernel: softmax over rules ----------------
__global__ __launch_bounds__(256) void k_softmax(const float* __restrict__ fsiniT,
                                                 float* __restrict__ fsT) {
    int b = blockIdx.x * 256 + threadIdx.x;  // 4096
    float v[32];
    float m = -1e30f;
#pragma unroll
    for (int r = 0; r < 32; ++r) { v[r] = fsiniT[r * 4096 + b]; m = fmaxf(m, v[r]); }
    float s = 0.f;
#pragma unroll
    for (int r = 0; r < 32; ++r) { v[r] = expf(v[r] - m); s += v[r]; }
    float inv = 1.f / s;
#pragma unroll
    for (int r = 0; r < 32; ++r) fsT[r * 4096 + b] = v[r] * inv;
}

// ---------------- kernel: A[b][k] = bf16(fs[b,r]*data[b,f]), pre-swizzled ----------------
__global__ __launch_bounds__(256) void k_scaleA(const float* __restrict__ data,
                                                const float* __restrict__ fsT,
                                                unsigned short* __restrict__ Asc) {
    int g = blockIdx.x * 256 + threadIdx.x;  // 4,194,304 = 4096 b * 1024 kg
    int b = g >> 10, kg = g & 1023;
    int r = kg >> 5, f0 = (kg & 31) << 3;
    float fs = fsT[r * 4096 + b];
    const float4* dp = (const float4*)(data + b * 256 + f0);
    float4 v0 = dp[0], v1 = dp[1];
    float vals[8] = {v0.x, v0.y, v0.z, v0.w, v1.x, v1.y, v1.z, v1.w};
    uint4 o;
    unsigned* op = (unsigned*)&o;
#pragma unroll
    for (int i = 0; i < 4; ++i) {
        unsigned lo = f2bf_rne(vals[2 * i] * fs);
        unsigned hi = f2bf_rne(vals[2 * i + 1] * fs);
        op[i] = lo | (hi << 16);
    }
    int byte = b * 16384 + ((kg & ~7) << 4) + (((kg & 7) ^ (b & 7)) << 4);
    *(uint4*)((char*)Asc + byte) = o;
}

// ---------------- kernel: GEMM [4096 x 8192] x [8192 x 1024] + fs@consq_b epilogue ----------------
// XCD-compact bid remap: XCD x (bid%8) gets mt in [4x,4x+4) x all nt -> per-K-step
// tile working set L2-resident and shared across the XCD's 32 co-resident blocks.
__global__ __launch_bounds__(512) void k_gemm(const unsigned short* __restrict__ Asc,
                                              const unsigned short* __restrict__ BT,
                                              const float* __restrict__ fsT,
                                              const float* __restrict__ cb,
                                              float* __restrict__ out) {
    __shared__ unsigned short As[8192];  // 128 rows x 64 k bf16 (swizzled)
    __shared__ unsigned short Bs[8192];  // 128 cols x 64 k bf16 (swizzled)
    int tid = threadIdx.x, lane = tid & 63, w = tid >> 6;
    int wm = w >> 2, wn = w & 3;
    int bid = blockIdx.x;
    int xcd = bid & 7, idx = bid >> 3;
    int mt = (xcd << 2) | (idx >> 3);
    int nt = idx & 7;
    int row0 = mt << 7, col0 = nt << 7;

    f32x4 acc[4][2] = {};

    const char* Ab = (const char*)Asc;
    const char* Bb = (const char*)BT;
    int flat0 = tid * 16, flat1 = tid * 16 + 8192;
    int rowl0 = flat0 >> 7, colB0 = flat0 & 127;
    int rowl1 = flat1 >> 7, colB1 = flat1 & 127;
    const char* aSrc0 = Ab + (row0 + rowl0) * 16384 + colB0;
    const char* aSrc1 = Ab + (row0 + rowl1) * 16384 + colB1;
    const char* bSrc0 = Bb + (col0 + rowl0) * 16384 + colB0;
    const char* bSrc1 = Bb + (col0 + rowl1) * 16384 + colB1;

    uint4 ra0 = *(const uint4*)aSrc0, ra1 = *(const uint4*)aSrc1;
    uint4 rb0 = *(const uint4*)bSrc0, rb1 = *(const uint4*)bSrc1;

    for (int kt = 0; kt < 128; ++kt) {
        __syncthreads();
        *(uint4*)((char*)As + flat0) = ra0;
        *(uint4*)((char*)As + flat1) = ra1;
        *(uint4*)((char*)Bs + flat0) = rb0;
        *(uint4*)((char*)Bs + flat1) = rb1;
        if (kt < 127) {
            int off = (kt + 1) << 7;
            ra0 = *(const uint4*)(aSrc0 + off);
            ra1 = *(const uint4*)(aSrc1 + off);
            rb0 = *(const uint4*)(bSrc0 + off);
            rb1 = *(const uint4*)(bSrc1 + off);
        }
        __syncthreads();
#pragma unroll
        for (int s = 0; s < 2; ++s) {
            bf16x8 af[4], bfv[2];
            int colByte = ((s << 5) + ((lane >> 4) << 3)) << 1;
#pragma unroll
            for (int mi = 0; mi < 4; ++mi) {
                int rowA = (wm << 6) + (mi << 4) + (lane & 15);
                int byte = (rowA << 7) + colByte;
                af[mi] = *(const bf16x8*)((const char*)As + (byte ^ ((rowA & 7) << 4)));
            }
#pragma unroll
            for (int ni = 0; ni < 2; ++ni) {
                int rowB = (wn << 5) + (ni << 4) + (lane & 15);
                int byte = (rowB << 7) + colByte;
                bfv[ni] = *(const bf16x8*)((const char*)Bs + (byte ^ ((rowB & 7) << 4)));
            }
#pragma unroll
            for (int mi = 0; mi < 4; ++mi)
#pragma unroll
                for (int ni = 0; ni < 2; ++ni)
                    acc[mi][ni] = __builtin_amdgcn_mfma_f32_16x16x32_bf16(af[mi], bfv[ni], acc[mi][ni], 0, 0, 0);
        }
    }

    int cA = col0 + (wn << 5) + (lane & 15);
    int cB2 = cA + 16;
    int rbase = row0 + (wm << 6) + ((lane >> 4) << 2);
    float bias[4][4][2];
#pragma unroll
    for (int mi = 0; mi < 4; ++mi)
#pragma unroll
        for (int q = 0; q < 4; ++q) { bias[mi][q][0] = 0.f; bias[mi][q][1] = 0.f; }

    for (int rr = 0; rr < 32; ++rr) {
        float cb0 = (cA < 1000) ? cb[rr * 1000 + cA] : 0.f;
        float cb1 = (cB2 < 1000) ? cb[rr * 1000 + cB2] : 0.f;
        const float* fcol = fsT + rr * 4096;
#pragma unroll
        for (int mi = 0; mi < 4; ++mi)
#pragma unroll
            for (int q = 0; q < 4; ++q) {
                float fsv = fcol[rbase + mi * 16 + q];
                bias[mi][q][0] += fsv * cb0;
                bias[mi][q][1] += fsv * cb1;
            }
    }
#pragma unroll
    for (int mi = 0; mi < 4; ++mi)
#pragma unroll
        for (int q = 0; q < 4; ++q) {
            int row = rbase + mi * 16 + q;
            if (cA < 1000) out[row * 1000 + cA] = acc[mi][0][q] + bias[mi][q][0];
            if (cB2 < 1000) out[row * 1000 + cB2] = acc[mi][1][q] + bias[mi][q][1];
        }
}

// ---------------- launch ----------------
extern "C" void kernel_launch(void* const* d_in, const int* in_sizes, int n_in,
                              void* d_out, int out_size, void* d_ws, size_t ws_size,
                              hipStream_t stream) {
    const float* data  = (const float*)d_in[0];
    const float* proto = (const float*)d_in[1];
    const float* w1    = (const float*)d_in[2];
    const float* b1    = (const float*)d_in[3];
    const float* w2    = (const float*)d_in[4];
    const float* b2    = (const float*)d_in[5];
    const float* fc1w  = (const float*)d_in[6];
    const float* fc1b  = (const float*)d_in[7];
    const float* fc2w  = (const float*)d_in[8];
    const float* fc2b  = (const float*)d_in[9];
    const float* cw    = (const float*)d_in[10];
    const float* cbias = (const float*)d_in[11];
    float* out = (float*)d_out;
    char* ws = (char*)d_ws;

    float* dTp             = (float*)(ws + OFF_DT);
    float* q1p             = (float*)(ws + OFF_Q1);
    float2* c1p            = (float2*)(ws + OFF_C1P);
    unsigned short* BT     = (unsigned short*)(ws + OFF_BT);
    unsigned short* W1s    = (unsigned short*)(ws + OFF_W1S);
    float* fsiniT          = (float*)(ws + OFF_FSI);
    float* fsT             = (float*)(ws + OFF_FS);
    unsigned short* Asc    = (unsigned short*)(ws + OFF_ASC);
    char* h2c              = (char*)(ws + OFF_H2);

    hipLaunchKernelGGL(k_transpose, dim3(256), dim3(256), 0, stream, data, dTp);
    hipLaunchKernelGGL(k_zrows, dim3(16), dim3(256), 0, stream, dTp);
    hipLaunchKernelGGL(k_prep_proto, dim3(32), dim3(256), 0, stream, proto, w1, b1, q1p);
    hipLaunchKernelGGL(k_prep_c1d, dim3(512), dim3(64), 0, stream, dTp, w1, c1p);
    hipLaunchKernelGGL(k_conv2, dim3(2048), dim3(64), 0, stream, c1p, q1p, w2, b2, h2c);
    // castB AFTER conv2: BT region aliases c1p
    hipLaunchKernelGGL(k_castB, dim3(4096), dim3(256), 0, stream, cw, BT);
    hipLaunchKernelGGL(k_castW, dim3(128), dim3(256), 0, stream, fc1w, W1s);
    hipLaunchKernelGGL(k_fc, dim3(1024), dim3(256), 0, stream,
                       h2c, (const char*)W1s, fc1b, fc2w, fc2b, fsiniT);
    hipLaunchKernelGGL(k_softmax, dim3(16), dim3(256), 0, stream, fsiniT, fsT);
    hipLaunchKernelGGL(k_scaleA, dim3(16384), dim3(256), 0, stream, data, fsT, Asc);
    hipLaunchKernelGGL(k_gemm, dim3(256), dim3(512), 0, stream, Asc, BT, fsT, cbias, out);
}